// Round 1
// 617.324 us; speedup vs baseline: 1.0199x; 1.0199x over previous
//
#include <hip/hip_runtime.h>

// Potts energy:  U (scalar) and U_i (N,C);  B=1, N=8192, K=32, C=21.
//
// v2: the scattered-gather version ran at ~0.73 TB/s effective (630 us vs a
// 74 us full-stream floor) because each wave's gather load fans out into 64
// independent 64-B-line transactions (stride 84 B < line). Fix: stream the
// whole 56.4 KB J-row per node fully coalesced into LDS with async
// global_load_lds (width=16, 1 KiB per wave-issue, no VGPR round-trip),
// then do the 672-element gather from LDS where it is essentially free.
//
// LDS: 57344 B row buffer (padded to 56 chunks of 1 KiB so the tail chunk's
// hardware lane-linear writes land in-pad) + small control arrays = 57.8 KB
// -> 2 blocks/CU, 8 waves/CU, ~112 KB of loads in flight per CU >> the
// ~10 KB latency-BW product -> HBM-bound at the stream rate.

#define KK 32
#define CC 21
#define ROWF (KK * CC * CC)          // 14112 floats per node
#define ROWB (ROWF * 4)              // 56448 bytes per node
#define NCHUNK 56                    // ceil(56448/1024): 1 KiB async chunks
#define ROWF_PAD (NCHUNK * 256)      // 14336 floats (57344 B) -- tail pad
#define PAIRS (KK * CC)              // 672 gathered elements per node

typedef __attribute__((address_space(3))) void       lds_void_t;
typedef __attribute__((address_space(1))) const void gbl_void_t;

__global__ __launch_bounds__(256) void potts_kernel(
    const int* __restrict__ S,
    const float* __restrict__ h,
    const float* __restrict__ J,
    const int* __restrict__ edge_idx,
    const float* __restrict__ mask_i,
    const float* __restrict__ mask_ij,
    float* __restrict__ out)            // out[0]=U, out[1..]=U_i (N*C)
{
    const int i    = blockIdx.x;
    const int tid  = threadIdx.x;
    const int wave = tid >> 6;
    const int lane = tid & 63;

    __shared__ float jrow[ROWF_PAD];
    __shared__ int   s_j[KK];
    __shared__ float m_ij[KK];
    __shared__ float acc[CC];
    __shared__ float ui_s[CC];

    const char* Jb = (const char*)(J + (size_t)i * ROWF);

    // ---- async coalesced stage: 56 x 1 KiB chunks, 4 waves x 14 issues ----
    // HW writes LDS at (uniform base + lane*16); global src is per-lane.
#pragma unroll
    for (int j = 0; j < 14; ++j) {
        int q       = (j << 2) + wave;       // chunk 0..55
        int lds_off = q << 10;               // byte offset into jrow
        int g_off   = lds_off + (lane << 4);
        if (g_off > ROWB - 16) g_off = ROWB - 16;  // tail: dup reads, pad writes
        __builtin_amdgcn_global_load_lds(
            (gbl_void_t*)(Jb + g_off),
            (lds_void_t*)((char*)jrow + lds_off),
            16, 0, 0);
    }

    if (tid < KK) {
        int e = edge_idx[i * KK + tid];
        s_j[tid]  = S[e];
        m_ij[tid] = mask_ij[i * KK + tid];
    }
    if (tid < CC) acc[tid] = 0.0f;
    __syncthreads();   // compiler drains vmcnt(0)+lgkmcnt(0) before s_barrier

    // ---- gather phase, now from LDS (stride 21 dwords = odd = conflict-light)
    float vals[3];
    int   cs[3];
#pragma unroll
    for (int j = 0; j < 3; ++j) {
        int idx = tid + j * 256;
        if (idx < PAIRS) {
            int k = idx / CC;                // magic-mul, compile-time const
            int c = idx - k * CC;
            cs[j]   = c;
            vals[j] = jrow[k * (CC * CC) + c * CC + s_j[k]] * m_ij[k];
        } else {
            cs[j]   = -1;
            vals[j] = 0.0f;
        }
    }
#pragma unroll
    for (int j = 0; j < 3; ++j) {
        if (cs[j] >= 0) atomicAdd(&acc[cs[j]], vals[j]);
    }
    __syncthreads();

    if (tid < CC) {
        float ui = h[i * CC + tid] * mask_i[i] + acc[tid];
        out[1 + i * CC + tid] = ui;
        ui_s[tid] = ui;
    }
    __syncthreads();

    if (tid == 0) {
        int s = S[i];
        float u = ui_s[s] - 0.5f * acc[s];
        atomicAdd(out, u);   // device-scope by default on CDNA
    }
}

extern "C" void kernel_launch(void* const* d_in, const int* in_sizes, int n_in,
                              void* d_out, int out_size, void* d_ws, size_t ws_size,
                              hipStream_t stream) {
    const int*   S        = (const int*)d_in[0];
    const float* h        = (const float*)d_in[1];
    const float* J        = (const float*)d_in[2];
    const int*   edge_idx = (const int*)d_in[3];
    const float* mask_i   = (const float*)d_in[4];
    const float* mask_ij  = (const float*)d_in[5];
    float* out = (float*)d_out;

    const int N = in_sizes[0];   // 8192 nodes

    // Harness poisons d_out with 0xAA; U is atomically accumulated -> zero it.
    hipMemsetAsync(out, 0, sizeof(float), stream);

    potts_kernel<<<N, 256, 0, stream>>>(S, h, J, edge_idx, mask_i, mask_ij, out);
}